// Round 7
// baseline (159.193 us; speedup 1.0000x reference)
//
#include <hip/hip_runtime.h>
#include <math.h>

// GraphConvLayer, round 7: channel-sliced L2-resident gather phases.
//  prep_tq:      feat f32 -> fp8, SLICE-MAJOR table tS[4][N][64] (3.2MB/slice)
//  prep_w:       W -> Wt (256,544) bf16 n-major
//  gather_slice: x4 sequential launches; phase s gathers only slice s ->
//                per-XCD L2 (4MiB) holds the whole 3.2MB slice -> gathers hit L2.
//                Writes agg (N,256) bf16 into ws.
//  gcl_gemm:     assemble mix (self f32->bf16, agg from ws, coord stats) ->
//                16x16x32 bf16 MFMA GEMM -> SiLU.
// Fallback to all-f32 single kernel if ws too small.

typedef __attribute__((ext_vector_type(8))) short short8;
typedef __attribute__((ext_vector_type(4))) float f32x4;
typedef __attribute__((ext_vector_type(2))) float f32x2;

constexpr int K = 32;
constexpr int C = 256;
constexpr int IN_DIM = 2 * C + 6;    // 518
constexpr int KP = 544;              // padded GEMM-K
constexpr int NT = 256;
constexpr int BMG = 64;              // rows per gather block
constexpr int BM = 16;               // rows per gemm block
constexpr int MIXS = 552;            // LDS row stride (bf16)
constexpr int SCH = 64;              // channels per slice
constexpr int NSLICE = 4;

__device__ __forceinline__ unsigned short f2bf(float f) {
  union { float f; unsigned u; } c; c.f = f;
  return (unsigned short)((c.u + 0x7fffu + ((c.u >> 16) & 1u)) >> 16);
}
__device__ __forceinline__ unsigned pack2(float lo, float hi) {
  return (unsigned)f2bf(lo) | ((unsigned)f2bf(hi) << 16);
}

// ---------------- prep kernels ----------------
__global__ __launch_bounds__(256)
void prep_tq(const float* __restrict__ feat, unsigned char* __restrict__ tS, int n) {
  int i = blockIdx.x * 256 + threadIdx.x;        // over n*32 chunks of 8 channels
  if (i < n * 32) {
    const int r = i >> 5, c8 = i & 31;
    const int ch0 = c8 * 8, s = ch0 >> 6, wi = ch0 & 63;
    const float4 v0 = *reinterpret_cast<const float4*>(feat + (size_t)r * C + ch0);
    const float4 v1 = *reinterpret_cast<const float4*>(feat + (size_t)r * C + ch0 + 4);
    unsigned a = 0, b = 0;
    a = __builtin_amdgcn_cvt_pk_fp8_f32(v0.x, v0.y, a, false);
    a = __builtin_amdgcn_cvt_pk_fp8_f32(v0.z, v0.w, a, true);
    b = __builtin_amdgcn_cvt_pk_fp8_f32(v1.x, v1.y, b, false);
    b = __builtin_amdgcn_cvt_pk_fp8_f32(v1.z, v1.w, b, true);
    uint2 o; o.x = a; o.y = b;
    *reinterpret_cast<uint2*>(tS + (size_t)s * n * SCH + (size_t)r * SCH + wi) = o;
  }
}

__global__ __launch_bounds__(256)
void prep_w(const float* __restrict__ W, unsigned short* __restrict__ Wt) {
  int i = blockIdx.x * 256 + threadIdx.x;        // over 256*544
  if (i < C * KP) {
    int nn = i / KP, k = i - nn * KP;
    float v = (k < IN_DIM) ? W[(size_t)k * C + nn] : 0.f;
    Wt[i] = f2bf(v);
  }
}

// ---------------- sliced gather kernel (one launch per slice) ----------------
__global__ __launch_bounds__(NT)
void gather_slice(const unsigned char* __restrict__ tS,
                  const int* __restrict__ knn,
                  unsigned short* __restrict__ agg,
                  int n, int slice)
{
  __shared__ int knnLds[BMG * K];                // 8 KB
  const int t = threadIdx.x;
  const int row0 = blockIdx.x * BMG;

  #pragma unroll
  for (int i = 0; i < (BMG * K) / NT; ++i) {     // 8 iters, coalesced
    int e = t + i * NT;
    int r = e >> 5, k = e & 31;
    int g = row0 + r; if (g >= n) g = n - 1;
    knnLds[e] = knn[(size_t)g * K + k];
  }
  __syncthreads();

  const int row = t >> 2;                        // 0..63
  const int lp  = t & 3;                         // 16B segment within 64B slice-row
  const unsigned char* base = tS + (size_t)slice * n * SCH + lp * 16;
  const int* ids = &knnLds[row * K];

  float a0=0,a1=0,a2=0,a3=0,a4=0,a5=0,a6=0,a7=0;
  float a8=0,a9=0,aA=0,aB=0,aC=0,aD=0,aE=0,aF=0;
  #pragma unroll 8
  for (int k = 0; k < K; ++k) {
    const uint4 v = *reinterpret_cast<const uint4*>(base + (size_t)ids[k] * SCH);
    f32x2 d0 = __builtin_amdgcn_cvt_pk_f32_fp8(v.x, false);
    f32x2 d1 = __builtin_amdgcn_cvt_pk_f32_fp8(v.x, true);
    f32x2 d2 = __builtin_amdgcn_cvt_pk_f32_fp8(v.y, false);
    f32x2 d3 = __builtin_amdgcn_cvt_pk_f32_fp8(v.y, true);
    f32x2 d4 = __builtin_amdgcn_cvt_pk_f32_fp8(v.z, false);
    f32x2 d5 = __builtin_amdgcn_cvt_pk_f32_fp8(v.z, true);
    f32x2 d6 = __builtin_amdgcn_cvt_pk_f32_fp8(v.w, false);
    f32x2 d7 = __builtin_amdgcn_cvt_pk_f32_fp8(v.w, true);
    a0 += d0.x; a1 += d0.y; a2 += d1.x; a3 += d1.y;
    a4 += d2.x; a5 += d2.y; a6 += d3.x; a7 += d3.y;
    a8 += d4.x; a9 += d4.y; aA += d5.x; aB += d5.y;
    aC += d6.x; aD += d6.y; aE += d7.x; aF += d7.y;
  }

  const int g = row0 + row;
  if (g < n) {
    const float s = 1.0f / 32.0f;
    uint4 o0, o1;
    o0.x = pack2(a0 * s, a1 * s); o0.y = pack2(a2 * s, a3 * s);
    o0.z = pack2(a4 * s, a5 * s); o0.w = pack2(a6 * s, a7 * s);
    o1.x = pack2(a8 * s, a9 * s); o1.y = pack2(aA * s, aB * s);
    o1.z = pack2(aC * s, aD * s); o1.w = pack2(aE * s, aF * s);
    unsigned short* dst = agg + (size_t)g * C + slice * SCH + lp * 16;
    *reinterpret_cast<uint4*>(dst)     = o0;
    *reinterpret_cast<uint4*>(dst + 8) = o1;
  }
}

// ---------------- mix assembly + MFMA GEMM ----------------
__global__ __launch_bounds__(NT)
void gcl_gemm(const float* __restrict__ feat,
              const unsigned short* __restrict__ agg,
              const float* __restrict__ coords,
              const int*   __restrict__ knn,
              const unsigned short* __restrict__ Wt,
              const float* __restrict__ bias,
              float* __restrict__ out, int n)
{
  __shared__ unsigned short mix[BM][MIXS];
  __shared__ int knnLds[BM * K];

  const int t = threadIdx.x;
  const int row0 = blockIdx.x * BM;

  #pragma unroll
  for (int i = 0; i < (BM * K) / NT; ++i) {
    int e = t + i * NT;
    int r = e >> 5, k = e & 31;
    int g = row0 + r; if (g >= n) g = n - 1;
    knnLds[e] = knn[(size_t)g * K + k];
  }
  for (int e = t; e < BM * (KP - IN_DIM); e += NT) {
    int r = e / (KP - IN_DIM), c = e - r * (KP - IN_DIM);
    mix[r][IN_DIM + c] = 0;
  }
  __syncthreads();

  const int w    = t >> 6;
  const int lane = t & 63;
  const int cl   = lane & 15;    // channel group cl*16..+15
  const int rq   = lane >> 4;    // row in quad

  // ---- self (f32 -> bf16) and agg (bf16 copy) into mix ----
  {
    const int r = (w << 2) + rq;
    int g = row0 + r; if (g >= n) g = n - 1;
    const float4 s0 = *reinterpret_cast<const float4*>(feat + (size_t)g * C + cl * 16 + 0);
    const float4 s1 = *reinterpret_cast<const float4*>(feat + (size_t)g * C + cl * 16 + 4);
    const float4 s2 = *reinterpret_cast<const float4*>(feat + (size_t)g * C + cl * 16 + 8);
    const float4 s3 = *reinterpret_cast<const float4*>(feat + (size_t)g * C + cl * 16 + 12);
    uint4 o0, o1;
    o0.x = pack2(s0.x, s0.y); o0.y = pack2(s0.z, s0.w);
    o0.z = pack2(s1.x, s1.y); o0.w = pack2(s1.z, s1.w);
    o1.x = pack2(s2.x, s2.y); o1.y = pack2(s2.z, s2.w);
    o1.z = pack2(s3.x, s3.y); o1.w = pack2(s3.z, s3.w);
    *reinterpret_cast<uint4*>(&mix[r][cl * 16 + 0]) = o0;
    *reinterpret_cast<uint4*>(&mix[r][cl * 16 + 8]) = o1;

    const uint4 g0 = *reinterpret_cast<const uint4*>(agg + (size_t)g * C + cl * 16 + 0);
    const uint4 g1 = *reinterpret_cast<const uint4*>(agg + (size_t)g * C + cl * 16 + 8);
    *reinterpret_cast<uint4*>(&mix[r][C + cl * 16 + 0]) = g0;
    *reinterpret_cast<uint4*>(&mix[r][C + cl * 16 + 8]) = g1;
  }

  // ---- coord stats: 32 lanes per row, shfl_xor tree reduce ----
  #pragma unroll
  for (int pass = 0; pass < 2; ++pass) {
    const int sr = (t >> 5) + pass * 8;
    const int sk = t & 31;
    const int id = knnLds[sr * K + sk];
    const float x = coords[(size_t)id * 3 + 0];
    const float y = coords[(size_t)id * 3 + 1];
    const float z = coords[(size_t)id * 3 + 2];
    float sx = x, sy = y, sz = z;
    float qx = x * x, qy = y * y, qz = z * z;
    #pragma unroll
    for (int m = 1; m < 32; m <<= 1) {
      sx += __shfl_xor(sx, m); sy += __shfl_xor(sy, m); sz += __shfl_xor(sz, m);
      qx += __shfl_xor(qx, m); qy += __shfl_xor(qy, m); qz += __shfl_xor(qz, m);
    }
    if (sk == 0) {
      int g = row0 + sr; if (g >= n) g = n - 1;
      const float inv = 1.0f / 32.0f;
      const float mx = sx * inv, my = sy * inv, mz = sz * inv;
      const float vx = qx * inv - mx * mx;
      const float vy = qy * inv - my * my;
      const float vz = qz * inv - mz * mz;
      mix[sr][2 * C + 0] = f2bf(mx - coords[(size_t)g * 3 + 0]);
      mix[sr][2 * C + 1] = f2bf(my - coords[(size_t)g * 3 + 1]);
      mix[sr][2 * C + 2] = f2bf(mz - coords[(size_t)g * 3 + 2]);
      mix[sr][2 * C + 3] = f2bf(sqrtf(fmaxf(vx, 0.f)));
      mix[sr][2 * C + 4] = f2bf(sqrtf(fmaxf(vy, 0.f)));
      mix[sr][2 * C + 5] = f2bf(sqrtf(fmaxf(vz, 0.f)));
    }
  }
  __syncthreads();

  // ---- MFMA GEMM: wave w -> cols w*64..+63, 16 rows ----
  const int n0  = w * 64;
  const int l15 = lane & 15;
  const int h   = lane >> 4;

  f32x4 acc[4];
  #pragma unroll
  for (int nt = 0; nt < 4; ++nt) acc[nt] = (f32x4){0.f, 0.f, 0.f, 0.f};

  const unsigned short* wbase = Wt + (size_t)(n0 + l15) * KP + 8 * h;

  #pragma unroll 1
  for (int s8 = 0; s8 < KP / 32; ++s8) {
    const int kb = s8 * 32;
    short8 A0 = *reinterpret_cast<const short8*>(&mix[l15][kb + 8 * h]);
    short8 B0 = *reinterpret_cast<const short8*>(wbase + 0 * 16 * KP + kb);
    short8 B1 = *reinterpret_cast<const short8*>(wbase + 1 * 16 * KP + kb);
    short8 B2 = *reinterpret_cast<const short8*>(wbase + 2 * 16 * KP + kb);
    short8 B3 = *reinterpret_cast<const short8*>(wbase + 3 * 16 * KP + kb);
    acc[0] = __builtin_amdgcn_mfma_f32_16x16x32_bf16(A0, B0, acc[0], 0, 0, 0);
    acc[1] = __builtin_amdgcn_mfma_f32_16x16x32_bf16(A0, B1, acc[1], 0, 0, 0);
    acc[2] = __builtin_amdgcn_mfma_f32_16x16x32_bf16(A0, B2, acc[2], 0, 0, 0);
    acc[3] = __builtin_amdgcn_mfma_f32_16x16x32_bf16(A0, B3, acc[3], 0, 0, 0);
  }

  #pragma unroll
  for (int nt = 0; nt < 4; ++nt) {
    const int col = n0 + nt * 16 + l15;
    const float bv = bias[col];
    f32x4 a = acc[nt];
    #pragma unroll
    for (int q = 0; q < 4; ++q) {
      const int grow = row0 + 4 * h + q;
      if (grow < n) {
        const float x = a[q] + bv;
        out[(size_t)grow * C + col] = x / (1.f + __expf(-x));
      }
    }
  }
}

// ---------------- all-f32 fallback (ws too small) ----------------
constexpr int BMF = 32;
constexpr int MIX_STRIDE = 520;

#define FMA4(mcomp, wv)                                                        \
  a.x = fmaf((mcomp), (wv).x, a.x);                                            \
  a.y = fmaf((mcomp), (wv).y, a.y);                                            \
  a.z = fmaf((mcomp), (wv).z, a.z);                                            \
  a.w = fmaf((mcomp), (wv).w, a.w);

__global__ __launch_bounds__(256, 2)
void gcl_fused(const float* __restrict__ feat,
               const float* __restrict__ coords,
               const int*   __restrict__ knn,
               const float* __restrict__ W,
               const float* __restrict__ bias,
               float* __restrict__ out,
               int n)
{
  __shared__ float mix[BMF][MIX_STRIDE];
  __shared__ int   knnLds[BMF * K];

  const int t = threadIdx.x;
  const int row0 = blockIdx.x * BMF;

  #pragma unroll
  for (int i = 0; i < (BMF * K) / 256; ++i) {
    const int e = t + i * 256;
    const int r = e >> 5;
    const int k = e & (K - 1);
    int grow = row0 + r; if (grow >= n) grow = n - 1;
    knnLds[e] = knn[(size_t)grow * K + k];
  }
  __syncthreads();

  const int c4 = t & 63;
  const int rg = t >> 6;

  for (int ri = 0; ri < BMF / 4; ++ri) {
    const int r = rg * (BMF / 4) + ri;
    int grow = row0 + r; if (grow >= n) grow = n - 1;
    const int* ids = &knnLds[r * K];
    float sx = 0.f, sy = 0.f, sz = 0.f, sw = 0.f;
    #pragma unroll 8
    for (int k = 0; k < K; ++k) {
      const float4 f = *reinterpret_cast<const float4*>(feat + (size_t)ids[k] * C + c4 * 4);
      sx += f.x; sy += f.y; sz += f.z; sw += f.w;
    }
    const float4 self = *reinterpret_cast<const float4*>(feat + (size_t)grow * C + c4 * 4);
    float* mr = mix[r];
    *reinterpret_cast<float4*>(mr + c4 * 4) = self;
    const float inv = 1.0f / (float)K;
    float4 a; a.x = sx * inv; a.y = sy * inv; a.z = sz * inv; a.w = sw * inv;
    *reinterpret_cast<float4*>(mr + C + c4 * 4) = a;
  }

  if (t < BMF * 3) {
    const int r = t / 3;
    const int d = t - r * 3;
    int grow = row0 + r; if (grow >= n) grow = n - 1;
    const int* ids = &knnLds[r * K];
    float s = 0.f, ss = 0.f;
    #pragma unroll 8
    for (int k = 0; k < K; ++k) {
      const float v = coords[(size_t)ids[k] * 3 + d];
      s += v; ss += v * v;
    }
    const float inv = 1.0f / (float)K;
    const float m = s * inv;
    const float var = ss * inv - m * m;
    mix[r][2 * C + d]     = m - coords[(size_t)grow * 3 + d];
    mix[r][2 * C + 3 + d] = sqrtf(fmaxf(var, 0.f));
  }
  __syncthreads();

  const int c0 = (t & 63) * 4;
  const int rbase = rg * (BMF / 4);

  float4 acc[BMF / 4];
  {
    const float4 bv = *reinterpret_cast<const float4*>(bias + c0);
    #pragma unroll
    for (int ri = 0; ri < BMF / 4; ++ri) acc[ri] = bv;
  }

  for (int jb = 0; jb < 129; ++jb) {
    const int j = jb * 4;
    const float4 w0 = *reinterpret_cast<const float4*>(W + (size_t)(j + 0) * C + c0);
    const float4 w1 = *reinterpret_cast<const float4*>(W + (size_t)(j + 1) * C + c0);
    const float4 w2 = *reinterpret_cast<const float4*>(W + (size_t)(j + 2) * C + c0);
    const float4 w3 = *reinterpret_cast<const float4*>(W + (size_t)(j + 3) * C + c0);
    #pragma unroll
    for (int ri = 0; ri < BMF / 4; ++ri) {
      const float4 m4 = *reinterpret_cast<const float4*>(&mix[rbase + ri][j]);
      float4 a = acc[ri];
      FMA4(m4.x, w0)
      FMA4(m4.y, w1)
      FMA4(m4.z, w2)
      FMA4(m4.w, w3)
      acc[ri] = a;
    }
  }
  #pragma unroll
  for (int jt = IN_DIM - 2; jt < IN_DIM; ++jt) {
    const float4 wv = *reinterpret_cast<const float4*>(W + (size_t)jt * C + c0);
    #pragma unroll
    for (int ri = 0; ri < BMF / 4; ++ri) {
      const float m = mix[rbase + ri][jt];
      float4 a = acc[ri];
      FMA4(m, wv)
      acc[ri] = a;
    }
  }

  #pragma unroll
  for (int ri = 0; ri < BMF / 4; ++ri) {
    const int grow = row0 + rbase + ri;
    if (grow < n) {
      float4 a = acc[ri];
      a.x = a.x / (1.f + expf(-a.x));
      a.y = a.y / (1.f + expf(-a.y));
      a.z = a.z / (1.f + expf(-a.z));
      a.w = a.w / (1.f + expf(-a.w));
      *reinterpret_cast<float4*>(out + (size_t)grow * C + c0) = a;
    }
  }
}

extern "C" void kernel_launch(void* const* d_in, const int* in_sizes, int n_in,
                              void* d_out, int out_size, void* d_ws, size_t ws_size,
                              hipStream_t stream) {
  const float* feat   = (const float*)d_in[0];
  const float* coords = (const float*)d_in[1];
  const int*   knn    = (const int*)d_in[2];
  const float* W      = (const float*)d_in[3];
  const float* bias   = (const float*)d_in[4];
  float* out = (float*)d_out;

  const int n = in_sizes[0] / C;                       // 50000

  const size_t tS_bytes  = (size_t)n * C;              // 12.8 MB (4 slices)
  const size_t wt_bytes  = (size_t)C * KP * 2;         // 278 KB
  const size_t agg_bytes = (size_t)n * C * 2;          // 25.6 MB
  const size_t need = tS_bytes + wt_bytes + agg_bytes; // ~38.7 MB

  if (ws_size >= need) {
    unsigned char*  tS  = (unsigned char*)d_ws;
    unsigned short* Wt  = (unsigned short*)((char*)d_ws + tS_bytes);
    unsigned short* agg = (unsigned short*)((char*)d_ws + tS_bytes + wt_bytes);

    hipLaunchKernelGGL(prep_tq, dim3((n * 32 + 255) / 256), dim3(256), 0, stream,
                       feat, tS, n);
    hipLaunchKernelGGL(prep_w, dim3((C * KP + 255) / 256), dim3(256), 0, stream, W, Wt);

    const int gridG = (n + BMG - 1) / BMG;             // 782
    for (int s = 0; s < NSLICE; ++s) {
      hipLaunchKernelGGL(gather_slice, dim3(gridG), dim3(NT), 0, stream,
                         tS, knn, agg, n, s);
    }

    const int gridM = (n + BM - 1) / BM;               // 3125
    hipLaunchKernelGGL(gcl_gemm, dim3(gridM), dim3(NT), 0, stream,
                       feat, agg, coords, knn, Wt, bias, out, n);
  } else {
    const int gridf = (n + BMF - 1) / BMF;
    hipLaunchKernelGGL(gcl_fused, dim3(gridf), dim3(256), 0, stream,
                       feat, coords, knn, W, bias, out, n);
  }
}

// Round 8
// 124.872 us; speedup vs baseline: 1.2749x; 1.2749x over previous
//
#include <hip/hip_runtime.h>
#include <math.h>

// GraphConvLayer, round 8: fused BM=32 (R3 base) + pipelined GEMM B-loads +
// cvt_pk_bf16 packing + 1/32 folded into Wt.
//  prep_feat_q: feat f32 -> fp8 e4m3 table in ws
//  prep_w:      W -> Wt (256,544) bf16 n-major, rows [C,2C) pre-scaled by 1/32
//  gcl_main:    fp8 gather-SUM -> LDS mix (bf16), wave-parallel coord stats,
//               16x16x32 bf16 MFMA GEMM with 1-deep register prefetch of A/B.

typedef __attribute__((ext_vector_type(8))) short short8;
typedef __attribute__((ext_vector_type(4))) float f32x4;
typedef __attribute__((ext_vector_type(2))) float f32x2;

constexpr int K = 32;
constexpr int C = 256;
constexpr int IN_DIM = 2 * C + 6;    // 518
constexpr int KP = 544;              // padded GEMM-K (17 * 32)
constexpr int BM = 32;               // rows per block
constexpr int MIXS = 552;            // LDS row stride (bf16)
constexpr int NT = 256;

__device__ __forceinline__ unsigned short f2bf(float f) {
  union { float f; unsigned u; } c; c.f = f;
  return (unsigned short)((c.u + 0x7fffu + ((c.u >> 16) & 1u)) >> 16);
}
// packed f32x2 -> bf16x2 in one VALU op (D.lo = bf16(lo), D.hi = bf16(hi))
__device__ __forceinline__ unsigned cvtpk(float lo, float hi) {
  unsigned r;
  asm("v_cvt_pk_bf16_f32 %0, %1, %2" : "=v"(r) : "v"(lo), "v"(hi));
  return r;
}

// ---------------- prep kernels ----------------
__global__ __launch_bounds__(256) void prep_feat_q(const float* __restrict__ feat,
                                                   uint2* __restrict__ featq,
                                                   long total8) {
  long i = (long)blockIdx.x * 256 + threadIdx.x;   // 8 floats -> uint2 of fp8
  if (i < total8) {
    const float4 v0 = reinterpret_cast<const float4*>(feat)[2 * i];
    const float4 v1 = reinterpret_cast<const float4*>(feat)[2 * i + 1];
    unsigned a = 0, b = 0;
    a = __builtin_amdgcn_cvt_pk_fp8_f32(v0.x, v0.y, a, false);
    a = __builtin_amdgcn_cvt_pk_fp8_f32(v0.z, v0.w, a, true);
    b = __builtin_amdgcn_cvt_pk_fp8_f32(v1.x, v1.y, b, false);
    b = __builtin_amdgcn_cvt_pk_fp8_f32(v1.z, v1.w, b, true);
    uint2 o; o.x = a; o.y = b;
    featq[i] = o;
  }
}

__global__ __launch_bounds__(256) void prep_w(const float* __restrict__ W,
                                              unsigned short* __restrict__ Wt) {
  int i = blockIdx.x * 256 + threadIdx.x;          // over 256*544
  if (i < C * KP) {
    int nn = i / KP, k = i - nn * KP;
    float v = (k < IN_DIM) ? W[(size_t)k * C + nn] : 0.f;
    if (k >= C && k < 2 * C) v *= (1.0f / 32.0f);  // fold mean scale into W
    Wt[i] = f2bf(v);
  }
}

// ---------------- main fused kernel ----------------
__global__ __launch_bounds__(NT, 4)
void gcl_main(const unsigned char* __restrict__ featq,   // fp8 table (N x C)
              const float* __restrict__ feat,            // original f32 (self rows)
              const float* __restrict__ coords,
              const int*   __restrict__ knn,
              const unsigned short* __restrict__ Wt,
              const float* __restrict__ bias,
              float* __restrict__ out, int n)
{
  __shared__ unsigned short mix[BM][MIXS];
  __shared__ int knnLds[BM * K];

  const int t = threadIdx.x;
  const int row0 = blockIdx.x * BM;

  // knn indices -> LDS (coalesced), 1024 ints
  #pragma unroll
  for (int i = 0; i < (BM * K) / NT; ++i) {
    int e = t + i * NT;
    int r = e >> 5, k = e & 31;
    int g = row0 + r; if (g >= n) g = n - 1;
    knnLds[e] = knn[(size_t)g * K + k];
  }
  // zero-pad mix cols 518..543
  for (int e = t; e < BM * (KP - IN_DIM); e += NT) {
    int r = e / (KP - IN_DIM), c = e - r * (KP - IN_DIM);
    mix[r][IN_DIM + c] = 0;
  }
  __syncthreads();

  const int w    = t >> 6;       // wave 0..3
  const int lane = t & 63;
  const int cl   = lane & 15;    // channel group: channels cl*16 .. cl*16+15
  const int rq   = lane >> 4;    // row-in-quad 0..3

  // ---- gather-SUM (fp8) + self copy (f32): wave w -> rows 8w..8w+7 ----
  #pragma unroll
  for (int p = 0; p < 2; ++p) {
    const int r = (w << 3) + (p << 2) + rq;
    int g = row0 + r; if (g >= n) g = n - 1;

    // self feature row, f32 -> bf16 (packed cvt)
    {
      const float4 s0 = *reinterpret_cast<const float4*>(feat + (size_t)g * C + cl * 16 + 0);
      const float4 s1 = *reinterpret_cast<const float4*>(feat + (size_t)g * C + cl * 16 + 4);
      const float4 s2 = *reinterpret_cast<const float4*>(feat + (size_t)g * C + cl * 16 + 8);
      const float4 s3 = *reinterpret_cast<const float4*>(feat + (size_t)g * C + cl * 16 + 12);
      uint4 o0, o1;
      o0.x = cvtpk(s0.x, s0.y); o0.y = cvtpk(s0.z, s0.w);
      o0.z = cvtpk(s1.x, s1.y); o0.w = cvtpk(s1.z, s1.w);
      o1.x = cvtpk(s2.x, s2.y); o1.y = cvtpk(s2.z, s2.w);
      o1.z = cvtpk(s3.x, s3.y); o1.w = cvtpk(s3.z, s3.w);
      *reinterpret_cast<uint4*>(&mix[r][cl * 16 + 0]) = o0;
      *reinterpret_cast<uint4*>(&mix[r][cl * 16 + 8]) = o1;
    }

    const int* ids = &knnLds[r * K];
    float a0=0,a1=0,a2=0,a3=0,a4=0,a5=0,a6=0,a7=0;
    float a8=0,a9=0,aA=0,aB=0,aC=0,aD=0,aE=0,aF=0;
    #pragma unroll 8
    for (int k = 0; k < K; ++k) {
      const uint4 v = *reinterpret_cast<const uint4*>(featq + (size_t)ids[k] * C + cl * 16);
      f32x2 d0 = __builtin_amdgcn_cvt_pk_f32_fp8(v.x, false);
      f32x2 d1 = __builtin_amdgcn_cvt_pk_f32_fp8(v.x, true);
      f32x2 d2 = __builtin_amdgcn_cvt_pk_f32_fp8(v.y, false);
      f32x2 d3 = __builtin_amdgcn_cvt_pk_f32_fp8(v.y, true);
      f32x2 d4 = __builtin_amdgcn_cvt_pk_f32_fp8(v.z, false);
      f32x2 d5 = __builtin_amdgcn_cvt_pk_f32_fp8(v.z, true);
      f32x2 d6 = __builtin_amdgcn_cvt_pk_f32_fp8(v.w, false);
      f32x2 d7 = __builtin_amdgcn_cvt_pk_f32_fp8(v.w, true);
      a0 += d0.x; a1 += d0.y; a2 += d1.x; a3 += d1.y;
      a4 += d2.x; a5 += d2.y; a6 += d3.x; a7 += d3.y;
      a8 += d4.x; a9 += d4.y; aA += d5.x; aB += d5.y;
      aC += d6.x; aD += d6.y; aE += d7.x; aF += d7.y;
    }
    // store SUM (1/32 folded into Wt rows [C,2C))
    uint4 o0, o1;
    o0.x = cvtpk(a0, a1); o0.y = cvtpk(a2, a3);
    o0.z = cvtpk(a4, a5); o0.w = cvtpk(a6, a7);
    o1.x = cvtpk(a8, a9); o1.y = cvtpk(aA, aB);
    o1.z = cvtpk(aC, aD); o1.w = cvtpk(aE, aF);
    *reinterpret_cast<uint4*>(&mix[r][C + cl * 16 + 0]) = o0;
    *reinterpret_cast<uint4*>(&mix[r][C + cl * 16 + 8]) = o1;
  }

  // ---- relative coordinate stats: 32 lanes per row, shfl_xor tree reduce ----
  #pragma unroll
  for (int pass = 0; pass < 4; ++pass) {
    const int sr = (t >> 5) + pass * 8;      // row 0..31
    const int sk = t & 31;                   // neighbor index
    const int id = knnLds[sr * K + sk];
    const float x = coords[(size_t)id * 3 + 0];
    const float y = coords[(size_t)id * 3 + 1];
    const float z = coords[(size_t)id * 3 + 2];
    float sx = x, sy = y, sz = z;
    float qx = x * x, qy = y * y, qz = z * z;
    #pragma unroll
    for (int m = 1; m < 32; m <<= 1) {
      sx += __shfl_xor(sx, m); sy += __shfl_xor(sy, m); sz += __shfl_xor(sz, m);
      qx += __shfl_xor(qx, m); qy += __shfl_xor(qy, m); qz += __shfl_xor(qz, m);
    }
    if (sk == 0) {
      int g = row0 + sr; if (g >= n) g = n - 1;
      const float inv = 1.0f / 32.0f;
      const float mx = sx * inv, my = sy * inv, mz = sz * inv;
      const float vx = qx * inv - mx * mx;
      const float vy = qy * inv - my * my;
      const float vz = qz * inv - mz * mz;
      mix[sr][2 * C + 0] = f2bf(mx - coords[(size_t)g * 3 + 0]);
      mix[sr][2 * C + 1] = f2bf(my - coords[(size_t)g * 3 + 1]);
      mix[sr][2 * C + 2] = f2bf(mz - coords[(size_t)g * 3 + 2]);
      mix[sr][2 * C + 3] = f2bf(sqrtf(fmaxf(vx, 0.f)));
      mix[sr][2 * C + 4] = f2bf(sqrtf(fmaxf(vy, 0.f)));
      mix[sr][2 * C + 5] = f2bf(sqrtf(fmaxf(vz, 0.f)));
    }
  }
  __syncthreads();

  // ---- MFMA GEMM: wave w -> cols w*64..+63, all 32 rows, pipelined B/A ----
  const int n0  = w * 64;
  const int l15 = lane & 15;
  const int h   = lane >> 4;

  f32x4 acc[2][4];
  #pragma unroll
  for (int mt = 0; mt < 2; ++mt)
    #pragma unroll
    for (int nt = 0; nt < 4; ++nt)
      acc[mt][nt] = (f32x4){0.f, 0.f, 0.f, 0.f};

  const unsigned short* wb = Wt + (size_t)(n0 + l15) * KP + 8 * h;

  // prologue: fetch step-0 operands
  short8 B0 = *reinterpret_cast<const short8*>(wb + 0 * 16 * KP);
  short8 B1 = *reinterpret_cast<const short8*>(wb + 1 * 16 * KP);
  short8 B2 = *reinterpret_cast<const short8*>(wb + 2 * 16 * KP);
  short8 B3 = *reinterpret_cast<const short8*>(wb + 3 * 16 * KP);
  short8 A0 = *reinterpret_cast<const short8*>(&mix[l15][8 * h]);
  short8 A1 = *reinterpret_cast<const short8*>(&mix[16 + l15][8 * h]);

  #pragma unroll 1
  for (int s8 = 0; s8 < KP / 32; ++s8) {
    const int kb  = s8 * 32;
    const int kbn = (kb + 32 <= KP - 32) ? kb + 32 : KP - 32;  // clamp (last reload harmless)
    // issue next-step loads before this step's MFMAs
    short8 nB0 = *reinterpret_cast<const short8*>(wb + 0 * 16 * KP + kbn);
    short8 nB1 = *reinterpret_cast<const short8*>(wb + 1 * 16 * KP + kbn);
    short8 nB2 = *reinterpret_cast<const short8*>(wb + 2 * 16 * KP + kbn);
    short8 nB3 = *reinterpret_cast<const short8*>(wb + 3 * 16 * KP + kbn);
    short8 nA0 = *reinterpret_cast<const short8*>(&mix[l15][kbn + 8 * h]);
    short8 nA1 = *reinterpret_cast<const short8*>(&mix[16 + l15][kbn + 8 * h]);

    acc[0][0] = __builtin_amdgcn_mfma_f32_16x16x32_bf16(A0, B0, acc[0][0], 0, 0, 0);
    acc[1][0] = __builtin_amdgcn_mfma_f32_16x16x32_bf16(A1, B0, acc[1][0], 0, 0, 0);
    acc[0][1] = __builtin_amdgcn_mfma_f32_16x16x32_bf16(A0, B1, acc[0][1], 0, 0, 0);
    acc[1][1] = __builtin_amdgcn_mfma_f32_16x16x32_bf16(A1, B1, acc[1][1], 0, 0, 0);
    acc[0][2] = __builtin_amdgcn_mfma_f32_16x16x32_bf16(A0, B2, acc[0][2], 0, 0, 0);
    acc[1][2] = __builtin_amdgcn_mfma_f32_16x16x32_bf16(A1, B2, acc[1][2], 0, 0, 0);
    acc[0][3] = __builtin_amdgcn_mfma_f32_16x16x32_bf16(A0, B3, acc[0][3], 0, 0, 0);
    acc[1][3] = __builtin_amdgcn_mfma_f32_16x16x32_bf16(A1, B3, acc[1][3], 0, 0, 0);

    B0 = nB0; B1 = nB1; B2 = nB2; B3 = nB3;
    A0 = nA0; A1 = nA1;
  }

  // ---- epilogue: bias + SiLU + store (C/D: col=lane&15, row=(lane>>4)*4+q) ----
  #pragma unroll
  for (int mt = 0; mt < 2; ++mt) {
    #pragma unroll
    for (int nt = 0; nt < 4; ++nt) {
      const int col = n0 + nt * 16 + l15;
      const float bv = bias[col];
      f32x4 a = acc[mt][nt];
      #pragma unroll
      for (int q = 0; q < 4; ++q) {
        const int grow = row0 + mt * 16 + 4 * h + q;
        if (grow < n) {
          const float x = a[q] + bv;
          out[(size_t)grow * C + col] = x * __builtin_amdgcn_rcpf(1.f + __expf(-x));
        }
      }
    }
  }
}

// ---------------- all-f32 fallback (ws too small) ----------------
constexpr int BMF = 32;
constexpr int MIX_STRIDE = 520;

#define FMA4(mcomp, wv)                                                        \
  a.x = fmaf((mcomp), (wv).x, a.x);                                            \
  a.y = fmaf((mcomp), (wv).y, a.y);                                            \
  a.z = fmaf((mcomp), (wv).z, a.z);                                            \
  a.w = fmaf((mcomp), (wv).w, a.w);

__global__ __launch_bounds__(256, 2)
void gcl_fused(const float* __restrict__ feat,
               const float* __restrict__ coords,
               const int*   __restrict__ knn,
               const float* __restrict__ W,
               const float* __restrict__ bias,
               float* __restrict__ out,
               int n)
{
  __shared__ float mix[BMF][MIX_STRIDE];
  __shared__ int   knnLds[BMF * K];

  const int t = threadIdx.x;
  const int row0 = blockIdx.x * BMF;

  #pragma unroll
  for (int i = 0; i < (BMF * K) / 256; ++i) {
    const int e = t + i * 256;
    const int r = e >> 5;
    const int k = e & (K - 1);
    int grow = row0 + r; if (grow >= n) grow = n - 1;
    knnLds[e] = knn[(size_t)grow * K + k];
  }
  __syncthreads();

  const int c4 = t & 63;
  const int rg = t >> 6;

  for (int ri = 0; ri < BMF / 4; ++ri) {
    const int r = rg * (BMF / 4) + ri;
    int grow = row0 + r; if (grow >= n) grow = n - 1;
    const int* ids = &knnLds[r * K];
    float sx = 0.f, sy = 0.f, sz = 0.f, sw = 0.f;
    #pragma unroll 8
    for (int k = 0; k < K; ++k) {
      const float4 f = *reinterpret_cast<const float4*>(feat + (size_t)ids[k] * C + c4 * 4);
      sx += f.x; sy += f.y; sz += f.z; sw += f.w;
    }
    const float4 self = *reinterpret_cast<const float4*>(feat + (size_t)grow * C + c4 * 4);
    float* mr = mix[r];
    *reinterpret_cast<float4*>(mr + c4 * 4) = self;
    const float inv = 1.0f / (float)K;
    float4 a; a.x = sx * inv; a.y = sy * inv; a.z = sz * inv; a.w = sw * inv;
    *reinterpret_cast<float4*>(mr + C + c4 * 4) = a;
  }

  if (t < BMF * 3) {
    const int r = t / 3;
    const int d = t - r * 3;
    int grow = row0 + r; if (grow >= n) grow = n - 1;
    const int* ids = &knnLds[r * K];
    float s = 0.f, ss = 0.f;
    #pragma unroll 8
    for (int k = 0; k < K; ++k) {
      const float v = coords[(size_t)ids[k] * 3 + d];
      s += v; ss += v * v;
    }
    const float inv = 1.0f / (float)K;
    const float m = s * inv;
    const float var = ss * inv - m * m;
    mix[r][2 * C + d]     = m - coords[(size_t)grow * 3 + d];
    mix[r][2 * C + 3 + d] = sqrtf(fmaxf(var, 0.f));
  }
  __syncthreads();

  const int c0 = (t & 63) * 4;
  const int rbase = rg * (BMF / 4);

  float4 acc[BMF / 4];
  {
    const float4 bv = *reinterpret_cast<const float4*>(bias + c0);
    #pragma unroll
    for (int ri = 0; ri < BMF / 4; ++ri) acc[ri] = bv;
  }

  for (int jb = 0; jb < 129; ++jb) {
    const int j = jb * 4;
    const float4 w0 = *reinterpret_cast<const float4*>(W + (size_t)(j + 0) * C + c0);
    const float4 w1 = *reinterpret_cast<const float4*>(W + (size_t)(j + 1) * C + c0);
    const float4 w2 = *reinterpret_cast<const float4*>(W + (size_t)(j + 2) * C + c0);
    const float4 w3 = *reinterpret_cast<const float4*>(W + (size_t)(j + 3) * C + c0);
    #pragma unroll
    for (int ri = 0; ri < BMF / 4; ++ri) {
      const float4 m4 = *reinterpret_cast<const float4*>(&mix[rbase + ri][j]);
      float4 a = acc[ri];
      FMA4(m4.x, w0)
      FMA4(m4.y, w1)
      FMA4(m4.z, w2)
      FMA4(m4.w, w3)
      acc[ri] = a;
    }
  }
  #pragma unroll
  for (int jt = IN_DIM - 2; jt < IN_DIM; ++jt) {
    const float4 wv = *reinterpret_cast<const float4*>(W + (size_t)jt * C + c0);
    #pragma unroll
    for (int ri = 0; ri < BMF / 4; ++ri) {
      const float m = mix[rbase + ri][jt];
      float4 a = acc[ri];
      FMA4(m, wv)
      acc[ri] = a;
    }
  }

  #pragma unroll
  for (int ri = 0; ri < BMF / 4; ++ri) {
    const int grow = row0 + rbase + ri;
    if (grow < n) {
      float4 a = acc[ri];
      a.x = a.x / (1.f + expf(-a.x));
      a.y = a.y / (1.f + expf(-a.y));
      a.z = a.z / (1.f + expf(-a.z));
      a.w = a.w / (1.f + expf(-a.w));
      *reinterpret_cast<float4*>(out + (size_t)grow * C + c0) = a;
    }
  }
}

extern "C" void kernel_launch(void* const* d_in, const int* in_sizes, int n_in,
                              void* d_out, int out_size, void* d_ws, size_t ws_size,
                              hipStream_t stream) {
  const float* feat   = (const float*)d_in[0];
  const float* coords = (const float*)d_in[1];
  const int*   knn    = (const int*)d_in[2];
  const float* W      = (const float*)d_in[3];
  const float* bias   = (const float*)d_in[4];
  float* out = (float*)d_out;

  const int n = in_sizes[0] / C;                 // 50000

  const size_t featq_bytes = (size_t)n * C;      // 12.8 MB fp8
  const size_t wt_bytes    = (size_t)C * KP * 2; // 278 KB

  if (ws_size >= featq_bytes + wt_bytes) {
    unsigned char* featq  = (unsigned char*)d_ws;
    unsigned short* Wt    = (unsigned short*)((char*)d_ws + featq_bytes);
    const long total8 = (long)n * C / 8;
    const int grid = (n + BM - 1) / BM;          // 1563
    hipLaunchKernelGGL(prep_feat_q, dim3((unsigned)((total8 + 255) / 256)), dim3(256), 0, stream,
                       feat, (uint2*)featq, total8);
    hipLaunchKernelGGL(prep_w, dim3((C * KP + 255) / 256), dim3(256), 0, stream, W, Wt);
    hipLaunchKernelGGL(gcl_main, dim3(grid), dim3(NT), 0, stream,
                       featq, feat, coords, knn, Wt, bias, out, n);
  } else {
    const int gridf = (n + BMF - 1) / BMF;
    hipLaunchKernelGGL(gcl_fused, dim3(gridf), dim3(256), 0, stream,
                       feat, coords, knn, W, bias, out, n);
  }
}

// Round 9
// 124.602 us; speedup vs baseline: 1.2776x; 1.0022x over previous
//
#include <hip/hip_runtime.h>
#include <math.h>

// GraphConvLayer, round 9: R8 + gather pipeline depth 8 -> 16 (#pragma unroll 16).
//  Theory: latency-bound gather; in-flight loads/CU = waves(16) x depth(16).
//  prep_feat_q: feat f32 -> fp8 e4m3 table in ws
//  prep_w:      W -> Wt (256,544) bf16 n-major, rows [C,2C) pre-scaled by 1/32
//  gcl_main:    fp8 gather-SUM -> LDS mix (bf16), wave-parallel coord stats,
//               16x16x32 bf16 MFMA GEMM with 1-deep register prefetch of A/B.

typedef __attribute__((ext_vector_type(8))) short short8;
typedef __attribute__((ext_vector_type(4))) float f32x4;
typedef __attribute__((ext_vector_type(2))) float f32x2;

constexpr int K = 32;
constexpr int C = 256;
constexpr int IN_DIM = 2 * C + 6;    // 518
constexpr int KP = 544;              // padded GEMM-K (17 * 32)
constexpr int BM = 32;               // rows per block
constexpr int MIXS = 552;            // LDS row stride (bf16)
constexpr int NT = 256;

__device__ __forceinline__ unsigned short f2bf(float f) {
  union { float f; unsigned u; } c; c.f = f;
  return (unsigned short)((c.u + 0x7fffu + ((c.u >> 16) & 1u)) >> 16);
}
// packed f32x2 -> bf16x2 in one VALU op
__device__ __forceinline__ unsigned cvtpk(float lo, float hi) {
  unsigned r;
  asm("v_cvt_pk_bf16_f32 %0, %1, %2" : "=v"(r) : "v"(lo), "v"(hi));
  return r;
}

// ---------------- prep kernels ----------------
__global__ __launch_bounds__(256) void prep_feat_q(const float* __restrict__ feat,
                                                   uint2* __restrict__ featq,
                                                   long total8) {
  long i = (long)blockIdx.x * 256 + threadIdx.x;   // 8 floats -> uint2 of fp8
  if (i < total8) {
    const float4 v0 = reinterpret_cast<const float4*>(feat)[2 * i];
    const float4 v1 = reinterpret_cast<const float4*>(feat)[2 * i + 1];
    unsigned a = 0, b = 0;
    a = __builtin_amdgcn_cvt_pk_fp8_f32(v0.x, v0.y, a, false);
    a = __builtin_amdgcn_cvt_pk_fp8_f32(v0.z, v0.w, a, true);
    b = __builtin_amdgcn_cvt_pk_fp8_f32(v1.x, v1.y, b, false);
    b = __builtin_amdgcn_cvt_pk_fp8_f32(v1.z, v1.w, b, true);
    uint2 o; o.x = a; o.y = b;
    featq[i] = o;
  }
}

__global__ __launch_bounds__(256) void prep_w(const float* __restrict__ W,
                                              unsigned short* __restrict__ Wt) {
  int i = blockIdx.x * 256 + threadIdx.x;          // over 256*544
  if (i < C * KP) {
    int nn = i / KP, k = i - nn * KP;
    float v = (k < IN_DIM) ? W[(size_t)k * C + nn] : 0.f;
    if (k >= C && k < 2 * C) v *= (1.0f / 32.0f);  // fold mean scale into W
    Wt[i] = f2bf(v);
  }
}

// ---------------- main fused kernel ----------------
__global__ __launch_bounds__(NT, 4)
void gcl_main(const unsigned char* __restrict__ featq,   // fp8 table (N x C)
              const float* __restrict__ feat,            // original f32 (self rows)
              const float* __restrict__ coords,
              const int*   __restrict__ knn,
              const unsigned short* __restrict__ Wt,
              const float* __restrict__ bias,
              float* __restrict__ out, int n)
{
  __shared__ unsigned short mix[BM][MIXS];
  __shared__ int knnLds[BM * K];

  const int t = threadIdx.x;
  const int row0 = blockIdx.x * BM;

  // knn indices -> LDS (coalesced), 1024 ints
  #pragma unroll
  for (int i = 0; i < (BM * K) / NT; ++i) {
    int e = t + i * NT;
    int r = e >> 5, k = e & 31;
    int g = row0 + r; if (g >= n) g = n - 1;
    knnLds[e] = knn[(size_t)g * K + k];
  }
  // zero-pad mix cols 518..543
  for (int e = t; e < BM * (KP - IN_DIM); e += NT) {
    int r = e / (KP - IN_DIM), c = e - r * (KP - IN_DIM);
    mix[r][IN_DIM + c] = 0;
  }
  __syncthreads();

  const int w    = t >> 6;       // wave 0..3
  const int lane = t & 63;
  const int cl   = lane & 15;    // channel group: channels cl*16 .. cl*16+15
  const int rq   = lane >> 4;    // row-in-quad 0..3

  // ---- gather-SUM (fp8) + self copy (f32): wave w -> rows 8w..8w+7 ----
  #pragma unroll
  for (int p = 0; p < 2; ++p) {
    const int r = (w << 3) + (p << 2) + rq;
    int g = row0 + r; if (g >= n) g = n - 1;

    // self feature row, f32 -> bf16 (packed cvt)
    {
      const float4 s0 = *reinterpret_cast<const float4*>(feat + (size_t)g * C + cl * 16 + 0);
      const float4 s1 = *reinterpret_cast<const float4*>(feat + (size_t)g * C + cl * 16 + 4);
      const float4 s2 = *reinterpret_cast<const float4*>(feat + (size_t)g * C + cl * 16 + 8);
      const float4 s3 = *reinterpret_cast<const float4*>(feat + (size_t)g * C + cl * 16 + 12);
      uint4 o0, o1;
      o0.x = cvtpk(s0.x, s0.y); o0.y = cvtpk(s0.z, s0.w);
      o0.z = cvtpk(s1.x, s1.y); o0.w = cvtpk(s1.z, s1.w);
      o1.x = cvtpk(s2.x, s2.y); o1.y = cvtpk(s2.z, s2.w);
      o1.z = cvtpk(s3.x, s3.y); o1.w = cvtpk(s3.z, s3.w);
      *reinterpret_cast<uint4*>(&mix[r][cl * 16 + 0]) = o0;
      *reinterpret_cast<uint4*>(&mix[r][cl * 16 + 8]) = o1;
    }

    const int* ids = &knnLds[r * K];
    float a0=0,a1=0,a2=0,a3=0,a4=0,a5=0,a6=0,a7=0;
    float a8=0,a9=0,aA=0,aB=0,aC=0,aD=0,aE=0,aF=0;
    #pragma unroll 16
    for (int k = 0; k < K; ++k) {
      const uint4 v = *reinterpret_cast<const uint4*>(featq + (size_t)ids[k] * C + cl * 16);
      f32x2 d0 = __builtin_amdgcn_cvt_pk_f32_fp8(v.x, false);
      f32x2 d1 = __builtin_amdgcn_cvt_pk_f32_fp8(v.x, true);
      f32x2 d2 = __builtin_amdgcn_cvt_pk_f32_fp8(v.y, false);
      f32x2 d3 = __builtin_amdgcn_cvt_pk_f32_fp8(v.y, true);
      f32x2 d4 = __builtin_amdgcn_cvt_pk_f32_fp8(v.z, false);
      f32x2 d5 = __builtin_amdgcn_cvt_pk_f32_fp8(v.z, true);
      f32x2 d6 = __builtin_amdgcn_cvt_pk_f32_fp8(v.w, false);
      f32x2 d7 = __builtin_amdgcn_cvt_pk_f32_fp8(v.w, true);
      a0 += d0.x; a1 += d0.y; a2 += d1.x; a3 += d1.y;
      a4 += d2.x; a5 += d2.y; a6 += d3.x; a7 += d3.y;
      a8 += d4.x; a9 += d4.y; aA += d5.x; aB += d5.y;
      aC += d6.x; aD += d6.y; aE += d7.x; aF += d7.y;
    }
    // store SUM (1/32 folded into Wt rows [C,2C))
    uint4 o0, o1;
    o0.x = cvtpk(a0, a1); o0.y = cvtpk(a2, a3);
    o0.z = cvtpk(a4, a5); o0.w = cvtpk(a6, a7);
    o1.x = cvtpk(a8, a9); o1.y = cvtpk(aA, aB);
    o1.z = cvtpk(aC, aD); o1.w = cvtpk(aE, aF);
    *reinterpret_cast<uint4*>(&mix[r][C + cl * 16 + 0]) = o0;
    *reinterpret_cast<uint4*>(&mix[r][C + cl * 16 + 8]) = o1;
  }

  // ---- relative coordinate stats: 32 lanes per row, shfl_xor tree reduce ----
  #pragma unroll
  for (int pass = 0; pass < 4; ++pass) {
    const int sr = (t >> 5) + pass * 8;      // row 0..31
    const int sk = t & 31;                   // neighbor index
    const int id = knnLds[sr * K + sk];
    const float x = coords[(size_t)id * 3 + 0];
    const float y = coords[(size_t)id * 3 + 1];
    const float z = coords[(size_t)id * 3 + 2];
    float sx = x, sy = y, sz = z;
    float qx = x * x, qy = y * y, qz = z * z;
    #pragma unroll
    for (int m = 1; m < 32; m <<= 1) {
      sx += __shfl_xor(sx, m); sy += __shfl_xor(sy, m); sz += __shfl_xor(sz, m);
      qx += __shfl_xor(qx, m); qy += __shfl_xor(qy, m); qz += __shfl_xor(qz, m);
    }
    if (sk == 0) {
      int g = row0 + sr; if (g >= n) g = n - 1;
      const float inv = 1.0f / 32.0f;
      const float mx = sx * inv, my = sy * inv, mz = sz * inv;
      const float vx = qx * inv - mx * mx;
      const float vy = qy * inv - my * my;
      const float vz = qz * inv - mz * mz;
      mix[sr][2 * C + 0] = f2bf(mx - coords[(size_t)g * 3 + 0]);
      mix[sr][2 * C + 1] = f2bf(my - coords[(size_t)g * 3 + 1]);
      mix[sr][2 * C + 2] = f2bf(mz - coords[(size_t)g * 3 + 2]);
      mix[sr][2 * C + 3] = f2bf(sqrtf(fmaxf(vx, 0.f)));
      mix[sr][2 * C + 4] = f2bf(sqrtf(fmaxf(vy, 0.f)));
      mix[sr][2 * C + 5] = f2bf(sqrtf(fmaxf(vz, 0.f)));
    }
  }
  __syncthreads();

  // ---- MFMA GEMM: wave w -> cols w*64..+63, all 32 rows, pipelined B/A ----
  const int n0  = w * 64;
  const int l15 = lane & 15;
  const int h   = lane >> 4;

  f32x4 acc[2][4];
  #pragma unroll
  for (int mt = 0; mt < 2; ++mt)
    #pragma unroll
    for (int nt = 0; nt < 4; ++nt)
      acc[mt][nt] = (f32x4){0.f, 0.f, 0.f, 0.f};

  const unsigned short* wb = Wt + (size_t)(n0 + l15) * KP + 8 * h;

  // prologue: fetch step-0 operands
  short8 B0 = *reinterpret_cast<const short8*>(wb + 0 * 16 * KP);
  short8 B1 = *reinterpret_cast<const short8*>(wb + 1 * 16 * KP);
  short8 B2 = *reinterpret_cast<const short8*>(wb + 2 * 16 * KP);
  short8 B3 = *reinterpret_cast<const short8*>(wb + 3 * 16 * KP);
  short8 A0 = *reinterpret_cast<const short8*>(&mix[l15][8 * h]);
  short8 A1 = *reinterpret_cast<const short8*>(&mix[16 + l15][8 * h]);

  #pragma unroll 1
  for (int s8 = 0; s8 < KP / 32; ++s8) {
    const int kb  = s8 * 32;
    const int kbn = (kb + 32 <= KP - 32) ? kb + 32 : KP - 32;  // clamp
    short8 nB0 = *reinterpret_cast<const short8*>(wb + 0 * 16 * KP + kbn);
    short8 nB1 = *reinterpret_cast<const short8*>(wb + 1 * 16 * KP + kbn);
    short8 nB2 = *reinterpret_cast<const short8*>(wb + 2 * 16 * KP + kbn);
    short8 nB3 = *reinterpret_cast<const short8*>(wb + 3 * 16 * KP + kbn);
    short8 nA0 = *reinterpret_cast<const short8*>(&mix[l15][kbn + 8 * h]);
    short8 nA1 = *reinterpret_cast<const short8*>(&mix[16 + l15][kbn + 8 * h]);

    acc[0][0] = __builtin_amdgcn_mfma_f32_16x16x32_bf16(A0, B0, acc[0][0], 0, 0, 0);
    acc[1][0] = __builtin_amdgcn_mfma_f32_16x16x32_bf16(A1, B0, acc[1][0], 0, 0, 0);
    acc[0][1] = __builtin_amdgcn_mfma_f32_16x16x32_bf16(A0, B1, acc[0][1], 0, 0, 0);
    acc[1][1] = __builtin_amdgcn_mfma_f32_16x16x32_bf16(A1, B1, acc[1][1], 0, 0, 0);
    acc[0][2] = __builtin_amdgcn_mfma_f32_16x16x32_bf16(A0, B2, acc[0][2], 0, 0, 0);
    acc[1][2] = __builtin_amdgcn_mfma_f32_16x16x32_bf16(A1, B2, acc[1][2], 0, 0, 0);
    acc[0][3] = __builtin_amdgcn_mfma_f32_16x16x32_bf16(A0, B3, acc[0][3], 0, 0, 0);
    acc[1][3] = __builtin_amdgcn_mfma_f32_16x16x32_bf16(A1, B3, acc[1][3], 0, 0, 0);

    B0 = nB0; B1 = nB1; B2 = nB2; B3 = nB3;
    A0 = nA0; A1 = nA1;
  }

  // ---- epilogue: bias + SiLU + store (C/D: col=lane&15, row=(lane>>4)*4+q) ----
  #pragma unroll
  for (int mt = 0; mt < 2; ++mt) {
    #pragma unroll
    for (int nt = 0; nt < 4; ++nt) {
      const int col = n0 + nt * 16 + l15;
      const float bv = bias[col];
      f32x4 a = acc[mt][nt];
      #pragma unroll
      for (int q = 0; q < 4; ++q) {
        const int grow = row0 + mt * 16 + 4 * h + q;
        if (grow < n) {
          const float x = a[q] + bv;
          out[(size_t)grow * C + col] = x * __builtin_amdgcn_rcpf(1.f + __expf(-x));
        }
      }
    }
  }
}

// ---------------- all-f32 fallback (ws too small) ----------------
constexpr int BMF = 32;
constexpr int MIX_STRIDE = 520;

#define FMA4(mcomp, wv)                                                        \
  a.x = fmaf((mcomp), (wv).x, a.x);                                            \
  a.y = fmaf((mcomp), (wv).y, a.y);                                            \
  a.z = fmaf((mcomp), (wv).z, a.z);                                            \
  a.w = fmaf((mcomp), (wv).w, a.w);

__global__ __launch_bounds__(256, 2)
void gcl_fused(const float* __restrict__ feat,
               const float* __restrict__ coords,
               const int*   __restrict__ knn,
               const float* __restrict__ W,
               const float* __restrict__ bias,
               float* __restrict__ out,
               int n)
{
  __shared__ float mix[BMF][MIX_STRIDE];
  __shared__ int   knnLds[BMF * K];

  const int t = threadIdx.x;
  const int row0 = blockIdx.x * BMF;

  #pragma unroll
  for (int i = 0; i < (BMF * K) / 256; ++i) {
    const int e = t + i * 256;
    const int r = e >> 5;
    const int k = e & (K - 1);
    int grow = row0 + r; if (grow >= n) grow = n - 1;
    knnLds[e] = knn[(size_t)grow * K + k];
  }
  __syncthreads();

  const int c4 = t & 63;
  const int rg = t >> 6;

  for (int ri = 0; ri < BMF / 4; ++ri) {
    const int r = rg * (BMF / 4) + ri;
    int grow = row0 + r; if (grow >= n) grow = n - 1;
    const int* ids = &knnLds[r * K];
    float sx = 0.f, sy = 0.f, sz = 0.f, sw = 0.f;
    #pragma unroll 8
    for (int k = 0; k < K; ++k) {
      const float4 f = *reinterpret_cast<const float4*>(feat + (size_t)ids[k] * C + c4 * 4);
      sx += f.x; sy += f.y; sz += f.z; sw += f.w;
    }
    const float4 self = *reinterpret_cast<const float4*>(feat + (size_t)grow * C + c4 * 4);
    float* mr = mix[r];
    *reinterpret_cast<float4*>(mr + c4 * 4) = self;
    const float inv = 1.0f / (float)K;
    float4 a; a.x = sx * inv; a.y = sy * inv; a.z = sz * inv; a.w = sw * inv;
    *reinterpret_cast<float4*>(mr + C + c4 * 4) = a;
  }

  if (t < BMF * 3) {
    const int r = t / 3;
    const int d = t - r * 3;
    int grow = row0 + r; if (grow >= n) grow = n - 1;
    const int* ids = &knnLds[r * K];
    float s = 0.f, ss = 0.f;
    #pragma unroll 8
    for (int k = 0; k < K; ++k) {
      const float v = coords[(size_t)ids[k] * 3 + d];
      s += v; ss += v * v;
    }
    const float inv = 1.0f / (float)K;
    const float m = s * inv;
    const float var = ss * inv - m * m;
    mix[r][2 * C + d]     = m - coords[(size_t)grow * 3 + d];
    mix[r][2 * C + 3 + d] = sqrtf(fmaxf(var, 0.f));
  }
  __syncthreads();

  const int c0 = (t & 63) * 4;
  const int rbase = rg * (BMF / 4);

  float4 acc[BMF / 4];
  {
    const float4 bv = *reinterpret_cast<const float4*>(bias + c0);
    #pragma unroll
    for (int ri = 0; ri < BMF / 4; ++ri) acc[ri] = bv;
  }

  for (int jb = 0; jb < 129; ++jb) {
    const int j = jb * 4;
    const float4 w0 = *reinterpret_cast<const float4*>(W + (size_t)(j + 0) * C + c0);
    const float4 w1 = *reinterpret_cast<const float4*>(W + (size_t)(j + 1) * C + c0);
    const float4 w2 = *reinterpret_cast<const float4*>(W + (size_t)(j + 2) * C + c0);
    const float4 w3 = *reinterpret_cast<const float4*>(W + (size_t)(j + 3) * C + c0);
    #pragma unroll
    for (int ri = 0; ri < BMF / 4; ++ri) {
      const float4 m4 = *reinterpret_cast<const float4*>(&mix[rbase + ri][j]);
      float4 a = acc[ri];
      FMA4(m4.x, w0)
      FMA4(m4.y, w1)
      FMA4(m4.z, w2)
      FMA4(m4.w, w3)
      acc[ri] = a;
    }
  }
  #pragma unroll
  for (int jt = IN_DIM - 2; jt < IN_DIM; ++jt) {
    const float4 wv = *reinterpret_cast<const float4*>(W + (size_t)jt * C + c0);
    #pragma unroll
    for (int ri = 0; ri < BMF / 4; ++ri) {
      const float m = mix[rbase + ri][jt];
      float4 a = acc[ri];
      FMA4(m, wv)
      acc[ri] = a;
    }
  }

  #pragma unroll
  for (int ri = 0; ri < BMF / 4; ++ri) {
    const int grow = row0 + rbase + ri;
    if (grow < n) {
      float4 a = acc[ri];
      a.x = a.x / (1.f + expf(-a.x));
      a.y = a.y / (1.f + expf(-a.y));
      a.z = a.z / (1.f + expf(-a.z));
      a.w = a.w / (1.f + expf(-a.w));
      *reinterpret_cast<float4*>(out + (size_t)grow * C + c0) = a;
    }
  }
}

extern "C" void kernel_launch(void* const* d_in, const int* in_sizes, int n_in,
                              void* d_out, int out_size, void* d_ws, size_t ws_size,
                              hipStream_t stream) {
  const float* feat   = (const float*)d_in[0];
  const float* coords = (const float*)d_in[1];
  const int*   knn    = (const int*)d_in[2];
  const float* W      = (const float*)d_in[3];
  const float* bias   = (const float*)d_in[4];
  float* out = (float*)d_out;

  const int n = in_sizes[0] / C;                 // 50000

  const size_t featq_bytes = (size_t)n * C;      // 12.8 MB fp8
  const size_t wt_bytes    = (size_t)C * KP * 2; // 278 KB

  if (ws_size >= featq_bytes + wt_bytes) {
    unsigned char* featq  = (unsigned char*)d_ws;
    unsigned short* Wt    = (unsigned short*)((char*)d_ws + featq_bytes);
    const long total8 = (long)n * C / 8;
    const int grid = (n + BM - 1) / BM;          // 1563
    hipLaunchKernelGGL(prep_feat_q, dim3((unsigned)((total8 + 255) / 256)), dim3(256), 0, stream,
                       feat, (uint2*)featq, total8);
    hipLaunchKernelGGL(prep_w, dim3((C * KP + 255) / 256), dim3(256), 0, stream, W, Wt);
    hipLaunchKernelGGL(gcl_main, dim3(grid), dim3(NT), 0, stream,
                       featq, feat, coords, knn, Wt, bias, out, n);
  } else {
    const int gridf = (n + BMF - 1) / BMF;
    hipLaunchKernelGGL(gcl_fused, dim3(gridf), dim3(256), 0, stream,
                       feat, coords, knn, W, bias, out, n);
  }
}